// Round 11
// baseline (320.357 us; speedup 1.0000x reference)
//
#include <hip/hip_runtime.h>

#define B_  8
#define S_  1024
#define D_  1024
#define H_  16
#define HD_ 64
#define M_  8192           // B*S
#define LOG2E 1.44269504088896f
#define QSCALE_ (0.125f * 1.44269504088896f)   // fold scale*log2e into Q
#define MSHIFT_ 20.0f      // static softmax shift (log2 domain)

typedef __attribute__((ext_vector_type(8))) short bf16x8;
typedef __attribute__((ext_vector_type(4))) short bf16x4;
typedef __attribute__((ext_vector_type(4))) float f32x4;

__device__ __forceinline__ unsigned short f2b(float x) {
  union { float f; unsigned u; } un; un.f = x;
  unsigned r = un.u + 0x7FFFu + ((un.u >> 16) & 1u);  // RNE
  return (unsigned short)(r >> 16);
}

// ---------------- kernel 0: hidden_states f32 -> bf16 ----------------
__global__ __launch_bounds__(256) void k_convert_x(const float* __restrict__ x,
                                                   unsigned short* __restrict__ o) {
  int i = (blockIdx.x * 256 + threadIdx.x) * 4;
  const int n = M_ * D_;
  const int stride = gridDim.x * 256 * 4;
  for (; i < n; i += stride) {
    const float4 v = *(const float4*)(x + i);
    ushort4 r;
    r.x = f2b(v.x); r.y = f2b(v.y); r.z = f2b(v.z); r.w = f2b(v.w);
    *(ushort4*)(o + i) = r;
  }
}

// ---------------- kernel 1: W (K x N) -> Wt bf16 (N x K), 3 matrices ----------------
__global__ __launch_bounds__(256) void k_transpose_w(const float* __restrict__ Wq,
    const float* __restrict__ Wk, const float* __restrict__ Wv,
    unsigned short* __restrict__ Wt) {
  __shared__ float t[64][65];
  const float* W = (blockIdx.z == 0) ? Wq : ((blockIdx.z == 1) ? Wk : Wv);
  unsigned short* dst = Wt + (size_t)blockIdx.z * (D_ * D_);
  const int k0 = blockIdx.x * 64, n0 = blockIdx.y * 64;
  const int tid = threadIdx.x;
#pragma unroll
  for (int i = 0; i < 16; ++i) {
    const int lin = i * 256 + tid;
    const int r = lin >> 6, c = lin & 63;
    t[r][c] = W[(size_t)(k0 + r) * D_ + n0 + c];
  }
  __syncthreads();
#pragma unroll
  for (int i = 0; i < 16; ++i) {
    const int lin = i * 256 + tid;
    const int r = lin >> 6, c = lin & 63;
    dst[(size_t)(n0 + r) * D_ + k0 + c] = f2b(t[c][r]);
  }
}

// ---------------- kernel 2: projection GEMM (m97 structure, 128x128x32) ----------------
template <int MODE>
__global__ __launch_bounds__(256) void k_proj(const unsigned short* __restrict__ X,
    const unsigned short* __restrict__ Wt,
    const float* __restrict__ bq, const float* __restrict__ bk, const float* __restrict__ bv,
    unsigned short* __restrict__ Qw, unsigned short* __restrict__ Kw,
    unsigned short* __restrict__ Vt) {
  __shared__ unsigned short xs[128 * 32];
  __shared__ unsigned short wsh[128 * 32];
  const int tid = threadIdx.x;
  const int lane = tid & 63, wv = tid >> 6;
  const int g = lane >> 4, li = lane & 15;
  const int m0 = blockIdx.x * 128;
  const int n0 = blockIdx.y * 128;
  const int wr = wv >> 1, wc = wv & 1;
  const int wtrow0 = (MODE == 0) ? n0 : (2048 + n0);

  f32x4 acc[4][4];
#pragma unroll
  for (int i = 0; i < 4; ++i)
#pragma unroll
    for (int j = 0; j < 4; ++j) acc[i][j] = (f32x4){0.f, 0.f, 0.f, 0.f};

  const int srow = wv * 32 + (lane >> 2);
  const int skel = (lane & 3) * 8;

  for (int k0 = 0; k0 < D_; k0 += 32) {
#pragma unroll
    for (int i = 0; i < 2; ++i) {
      const unsigned short* gx = X + (size_t)(m0 + srow + i * 16) * D_ + k0 + skel;
      const unsigned short* gw = Wt + (size_t)(wtrow0 + srow + i * 16) * D_ + k0 + skel;
      __builtin_amdgcn_global_load_lds(
          (const __attribute__((address_space(1))) void*)gx,
          (__attribute__((address_space(3))) void*)&xs[(wv * 32 + i * 16) * 32], 16, 0, 0);
      __builtin_amdgcn_global_load_lds(
          (const __attribute__((address_space(1))) void*)gw,
          (__attribute__((address_space(3))) void*)&wsh[(wv * 32 + i * 16) * 32], 16, 0, 0);
    }
    __syncthreads();
    bf16x8 af[4], bfr[4];
#pragma unroll
    for (int i = 0; i < 4; ++i) {
      const int ar = wr * 64 + i * 16 + li;
      const int br = wc * 64 + i * 16 + li;
      if (MODE == 0) {
        af[i]  = *(const bf16x8*)&xs[ar * 32 + g * 8];
        bfr[i] = *(const bf16x8*)&wsh[br * 32 + g * 8];
      } else {
        af[i]  = *(const bf16x8*)&wsh[ar * 32 + g * 8];
        bfr[i] = *(const bf16x8*)&xs[br * 32 + g * 8];
      }
    }
#pragma unroll
    for (int i = 0; i < 4; ++i)
#pragma unroll
      for (int j = 0; j < 4; ++j)
        acc[i][j] = __builtin_amdgcn_mfma_f32_16x16x32_bf16(af[i], bfr[j], acc[i][j], 0, 0, 0);
    __syncthreads();
  }

  if (MODE == 0) {
#pragma unroll
    for (int j = 0; j < 4; ++j) {
      const int n = n0 + wc * 64 + j * 16 + li;
      const float bias = (n < D_) ? bq[n] : bk[n - D_];
#pragma unroll
      for (int i = 0; i < 4; ++i) {
#pragma unroll
        for (int r = 0; r < 4; ++r) {
          const int m = m0 + wr * 64 + i * 16 + g * 4 + r;
          const float v = acc[i][j][r] + bias;
          const int bb = m >> 10, ss = m & 1023;
          if (n < D_) {
            Qw[((size_t)(bb * H_ + (n >> 6)) * S_ + ss) * HD_ + (n & 63)] = f2b(v * QSCALE_);
          } else {
            const int nk = n - D_;
            Kw[((size_t)(bb * H_ + (nk >> 6)) * S_ + ss) * HD_ + (nk & 63)] = f2b(v);
          }
        }
      }
    }
  } else {
#pragma unroll
    for (int i = 0; i < 4; ++i) {
#pragma unroll
      for (int r = 0; r < 4; ++r) {
        const int nv = n0 + wr * 64 + i * 16 + g * 4 + r;
        const float bias = bv[nv];
#pragma unroll
        for (int j = 0; j < 4; ++j) {
          const int m = m0 + wc * 64 + j * 16 + li;
          const int bb = m >> 10, ss = m & 1023;
          const float v = acc[i][j][r] + bias;
          Vt[((size_t)(bb * H_ + (nv >> 6)) * HD_ + (nv & 63)) * S_ + ss] = f2b(v);
        }
      }
    }
  }
}

// ---------------- kernel 3: flash attention, kv-split waves, lane-local P ----------------
// Wave wv owns kv slice [wv*16, wv*16+16) of each 64-kv tile, for ALL 64 q rows.
// Swapped QK (mfma(K,Q)) puts P[kv=4g+j][q=li] in-lane; PV uses the compressed-slot
// trick: both V (A-op) and P (B-op) place kv=4g+e at MFMA k-slot 8g+e with zeros in
// e>=4 -> dot product is the exact 16-kv sum, zero cross-lane traffic, no P bounce.
// All staged data is per-wave-private -> NO in-loop barriers; each wave free-runs its
// own counted-vmcnt(12) double-buffered pipeline. One syncthreads before the epilogue
// cross-wave exchange (LDS aliased after full vmcnt(0) drain).
__global__ __launch_bounds__(256, 2) void k_attn(const unsigned short* __restrict__ Qw,
    const unsigned short* __restrict__ Kw, const unsigned short* __restrict__ Vt,
    const float* __restrict__ prev, const float* __restrict__ mask,
    float* __restrict__ out) {
  // smem (bytes):
  //   [0,16384)      K: [buf][wave] 2KB (16 kv x 64 d, src-XOR-swizzled 16B chunks)
  //   [16384,32768)  V: [buf][wave] 2KB (64 d x 16 kv, 32B rows, linear)
  //   [32768,65536)  prev: [buf][wave] 4KB (4 qb x 64 lanes x 16B, lane-linear)
  //   [65536,66560)  lsum float[4][4][16]
  //   epilogue: [0,65536) reused as ctx exchange (after vmcnt(0)+syncthreads)
  __shared__ __align__(16) char smem[66560];
  const int tid = threadIdx.x;
  const int lane = tid & 63, wv = tid >> 6;
  const int g = lane >> 4, li = lane & 15;

  const int phys = blockIdx.x + 16 * blockIdx.y;  // 0..2047
  const int b  = phys & 7;                        // XCD-locked batch
  const int qt = (phys >> 3) & 15;
  const int h  = phys >> 7;
  const int bh = b * H_ + h;

  const unsigned short* kbase = Kw + (size_t)bh * S_ * HD_;
  const unsigned short* vbase = Vt + (size_t)bh * HD_ * S_;
  const float* pbase = prev + (size_t)bh * S_ * S_ + (size_t)(qt * 64 + li) * S_ + wv * 16 + g * 4;
  const float* mb    = mask + (size_t)b * S_ * S_ + (size_t)(qt * 64 + li) * S_ + wv * 16 + g * 4;

  // per-lane DMA source offsets (global side carries the swizzle; LDS dest is linear)
  const int koff = (wv * 16 + (lane >> 3)) * HD_ + (((lane & 7) ^ (lane >> 3)) << 3);
  const int voff = (lane >> 1) * S_ + wv * 16 + ((lane & 1) << 3);

  // Q fragments (B-operand of QK): 4 q-blocks x 2 d-halves, pre-scaled by SCALE*LOG2E
  bf16x8 qA[4], qB[4];
#pragma unroll
  for (int qb = 0; qb < 4; ++qb) {
    const unsigned short* qp = Qw + ((size_t)bh * S_ + qt * 64 + qb * 16 + li) * HD_ + g * 8;
    qA[qb] = *(const bf16x8*)qp;
    qB[qb] = *(const bf16x8*)(qp + 32);
  }

  // 8 global_load_lds per phase per wave: K(2) V(2) prev(4)
#define STAGE(TN, BI)                                                                      \
  {                                                                                        \
    const int t64 = (TN) * 64;                                                             \
    __builtin_amdgcn_global_load_lds(                                                      \
        (const __attribute__((address_space(1))) void*)(kbase + (size_t)t64 * HD_ + koff), \
        (__attribute__((address_space(3))) void*)(smem + (BI) * 8192 + wv * 2048), 16, 0, 0); \
    __builtin_amdgcn_global_load_lds(                                                      \
        (const __attribute__((address_space(1))) void*)(kbase + (size_t)t64 * HD_ + koff + 512), \
        (__attribute__((address_space(3))) void*)(smem + (BI) * 8192 + wv * 2048 + 1024), 16, 0, 0); \
    __builtin_amdgcn_global_load_lds(                                                      \
        (const __attribute__((address_space(1))) void*)(vbase + voff + t64),               \
        (__attribute__((address_space(3))) void*)(smem + 16384 + (BI) * 8192 + wv * 2048), 16, 0, 0); \
    __builtin_amdgcn_global_load_lds(                                                      \
        (const __attribute__((address_space(1))) void*)(vbase + voff + 32 * S_ + t64),     \
        (__attribute__((address_space(3))) void*)(smem + 16384 + (BI) * 8192 + wv * 2048 + 1024), 16, 0, 0); \
    _Pragma("unroll")                                                                      \
    for (int pq = 0; pq < 4; ++pq)                                                         \
      __builtin_amdgcn_global_load_lds(                                                    \
          (const __attribute__((address_space(1))) void*)(pbase + (size_t)pq * 16 * S_ + t64), \
          (__attribute__((address_space(3))) void*)(smem + 32768 + (BI) * 16384 + wv * 4096 + pq * 1024), 16, 0, 0); \
  }

  float lrun[4] = {0.f, 0.f, 0.f, 0.f};
  f32x4 ctx[4][4];   // [db][qb]: D[d = db*16 + 4g + r][q = qb*16 + li], wave's kv partial
#pragma unroll
  for (int d = 0; d < 4; ++d)
#pragma unroll
    for (int q = 0; q < 4; ++q) ctx[d][q] = (f32x4){0.f, 0.f, 0.f, 0.f};

  f32x4 mA[4], mB[4];

  // prologue: stage tile 0 + mask(0)  (12 VMEM ops in flight)
  STAGE(0, 0);
#pragma unroll
  for (int qb = 0; qb < 4; ++qb) mA[qb] = *(const f32x4*)(mb + (size_t)qb * 16 * S_);

  // Per phase: STAGE(t+1)+mask(t+1) [12 ops] -> vmcnt(12) proves tile t landed while
  // the new 12 stay in flight. No barriers: every buffer is per-wave-private.
#define PHASE(T, PB, NB, MCUR, MNXT)                                                  \
  {                                                                                   \
    const int tn = ((T) < 15) ? (T) + 1 : 15;                                         \
    STAGE(tn, NB);                                                                    \
    _Pragma("unroll")                                                                 \
    for (int qb = 0; qb < 4; ++qb)                                                    \
      MNXT[qb] = *(const f32x4*)(mb + (size_t)qb * 16 * S_ + tn * 64);                \
    asm volatile("s_waitcnt vmcnt(12)" ::: "memory");                                 \
    __builtin_amdgcn_sched_barrier(0);                                                \
    {                                                                                 \
      const char* kb  = smem + (PB) * 8192 + wv * 2048;                               \
      const char* vb  = smem + 16384 + (PB) * 8192 + wv * 2048;                       \
      const char* pmw = smem + 32768 + (PB) * 16384 + wv * 4096;                      \
      const bf16x8 kf0 = *(const bf16x8*)(kb + li * 128 + ((g ^ (li & 7)) << 4));     \
      const bf16x8 kf1 = *(const bf16x8*)(kb + li * 128 + (((4 + g) ^ (li & 7)) << 4)); \
      f32x4 sa[4];                                                                    \
      _Pragma("unroll")                                                               \
      for (int qb = 0; qb < 4; ++qb) {                                                \
        f32x4 z = (f32x4){0.f, 0.f, 0.f, 0.f};                                        \
        z      = __builtin_amdgcn_mfma_f32_16x16x32_bf16(kf0, qA[qb], z, 0, 0, 0);    \
        sa[qb] = __builtin_amdgcn_mfma_f32_16x16x32_bf16(kf1, qB[qb], z, 0, 0, 0);    \
      }                                                                               \
      bf16x8 pk[4];                                                                   \
      _Pragma("unroll")                                                               \
      for (int qb = 0; qb < 4; ++qb) {                                                \
        const f32x4 pv = *(const f32x4*)(pmw + qb * 1024 + lane * 16);                \
        const float e0 = exp2f(sa[qb][0] + fmaf(pv[0] + MCUR[qb][0], LOG2E, -MSHIFT_)); \
        const float e1 = exp2f(sa[qb][1] + fmaf(pv[1] + MCUR[qb][1], LOG2E, -MSHIFT_)); \
        const float e2 = exp2f(sa[qb][2] + fmaf(pv[2] + MCUR[qb][2], LOG2E, -MSHIFT_)); \
        const float e3 = exp2f(sa[qb][3] + fmaf(pv[3] + MCUR[qb][3], LOG2E, -MSHIFT_)); \
        lrun[qb] += (e0 + e1) + (e2 + e3);                                            \
        union { unsigned short s[8]; bf16x8 v; } c8;                                  \
        c8.s[0] = f2b(e0); c8.s[1] = f2b(e1); c8.s[2] = f2b(e2); c8.s[3] = f2b(e3);   \
        c8.s[4] = 0; c8.s[5] = 0; c8.s[6] = 0; c8.s[7] = 0;                           \
        pk[qb] = c8.v;                                                                \
      }                                                                               \
      _Pragma("unroll")                                                               \
      for (int db = 0; db < 4; ++db) {                                                \
        const bf16x4 v4 = *(const bf16x4*)(vb + (db * 16 + li) * 32 + g * 8);         \
        const bf16x8 vf = (bf16x8){v4[0], v4[1], v4[2], v4[3], 0, 0, 0, 0};           \
        _Pragma("unroll")                                                             \
        for (int qb = 0; qb < 4; ++qb)                                                \
          ctx[db][qb] = __builtin_amdgcn_mfma_f32_16x16x32_bf16(vf, pk[qb], ctx[db][qb], 0, 0, 0); \
      }                                                                               \
    }                                                                                 \
  }

  for (int t = 0; t < 16; t += 2) {
    PHASE(t,     0, 1, mA, mB);
    PHASE(t + 1, 1, 0, mB, mA);
  }
#undef PHASE
#undef STAGE

  // ---- epilogue: full drain, then alias buffers as the cross-wave ctx exchange ----
  asm volatile("s_waitcnt vmcnt(0)" ::: "memory");
  __builtin_amdgcn_sched_barrier(0);
  __syncthreads();

  float* ex = (float*)smem;                 // [w][db][qb][lane][4]
#pragma unroll
  for (int db = 0; db < 4; ++db)
#pragma unroll
    for (int qb = 0; qb < 4; ++qb)
      *(f32x4*)(ex + ((((wv * 4 + db) * 4 + qb) * 64) + lane) * 4) = ctx[db][qb];

  // wave-local rowsum over its 16 kv (combine g-groups), stash per wave
#pragma unroll
  for (int qb = 0; qb < 4; ++qb) {
    lrun[qb] += __shfl_xor(lrun[qb], 16);
    lrun[qb] += __shfl_xor(lrun[qb], 32);
  }
  float* ls = (float*)(smem + 65536);       // [w][qb][li]
  if (g == 0) {
#pragma unroll
    for (int qb = 0; qb < 4; ++qb) ls[(wv * 4 + qb) * 16 + li] = lrun[qb];
  }
  __syncthreads();

  // each wave finalizes d-block db = wv: sum the 4 kv-partials, normalize, write
#pragma unroll
  for (int qb = 0; qb < 4; ++qb) {
    const float tot = ls[(0 * 4 + qb) * 16 + li] + ls[(1 * 4 + qb) * 16 + li] +
                      ls[(2 * 4 + qb) * 16 + li] + ls[(3 * 4 + qb) * 16 + li];
    const float inv = 1.0f / tot;
    f32x4 a0 = *(const f32x4*)(ex + ((((0 * 4 + wv) * 4 + qb) * 64) + lane) * 4);
    f32x4 a1 = *(const f32x4*)(ex + ((((1 * 4 + wv) * 4 + qb) * 64) + lane) * 4);
    f32x4 a2 = *(const f32x4*)(ex + ((((2 * 4 + wv) * 4 + qb) * 64) + lane) * 4);
    f32x4 a3 = *(const f32x4*)(ex + ((((3 * 4 + wv) * 4 + qb) * 64) + lane) * 4);
    float4 o;
    o.x = (a0[0] + a1[0] + a2[0] + a3[0]) * inv;
    o.y = (a0[1] + a1[1] + a2[1] + a3[1]) * inv;
    o.z = (a0[2] + a1[2] + a2[2] + a3[2]) * inv;
    o.w = (a0[3] + a1[3] + a2[3] + a3[3]) * inv;
    *(float4*)(out + ((size_t)(b * S_ + qt * 64 + qb * 16 + li)) * D_ +
               h * HD_ + wv * 16 + g * 4) = o;
  }
}

extern "C" void kernel_launch(void* const* d_in, const int* in_sizes, int n_in,
                              void* d_out, int out_size, void* d_ws, size_t ws_size,
                              hipStream_t stream) {
  const float* hs   = (const float*)d_in[0];
  const float* mask = (const float*)d_in[1];
  const float* prev = (const float*)d_in[2];
  const float* Wq   = (const float*)d_in[3];
  const float* bq   = (const float*)d_in[4];
  const float* Wk   = (const float*)d_in[5];
  const float* bk   = (const float*)d_in[6];
  const float* Wv   = (const float*)d_in[7];
  const float* bv   = (const float*)d_in[8];
  float* out = (float*)d_out;

  char* ws = (char*)d_ws;
  unsigned short* Xbf = (unsigned short*)ws;                    // 16 MB
  unsigned short* Wt  = (unsigned short*)(ws + (16ull << 20));  //  6 MB
  unsigned short* Qw  = (unsigned short*)(ws + (22ull << 20));  // 16 MB
  unsigned short* Kw  = (unsigned short*)(ws + (38ull << 20));  // 16 MB
  unsigned short* Vt  = (unsigned short*)(ws + (54ull << 20));  // 16 MB  (total 70 MB)

  k_convert_x<<<2048, 256, 0, stream>>>(hs, Xbf);
  k_transpose_w<<<dim3(16, 16, 3), 256, 0, stream>>>(Wq, Wk, Wv, Wt);
  k_proj<0><<<dim3(64, 16), 256, 0, stream>>>(Xbf, Wt, bq, bk, bv, Qw, Kw, Vt);
  k_proj<1><<<dim3(64, 8),  256, 0, stream>>>(Xbf, Wt, bq, bk, bv, Qw, Kw, Vt);
  k_attn<<<dim3(16, 128), 256, 0, stream>>>(Qw, Kw, Vt, prev, mask, out);
}

// Round 12
// 294.381 us; speedup vs baseline: 1.0882x; 1.0882x over previous
//
#include <hip/hip_runtime.h>

#define B_  8
#define S_  1024
#define D_  1024
#define H_  16
#define HD_ 64
#define M_  8192           // B*S
#define LOG2E 1.44269504088896f
#define QSCALE_ (0.125f * 1.44269504088896f)   // fold scale*log2e into Q
#define MSHIFT_ 20.0f      // static softmax shift (log2 domain)

typedef __attribute__((ext_vector_type(8))) short bf16x8;
typedef __attribute__((ext_vector_type(4))) float f32x4;

__device__ __forceinline__ unsigned short f2b(float x) {
  union { float f; unsigned u; } un; un.f = x;
  unsigned r = un.u + 0x7FFFu + ((un.u >> 16) & 1u);  // RNE
  return (unsigned short)(r >> 16);
}

// ---------------- kernel 0: hidden_states f32 -> bf16 ----------------
__global__ __launch_bounds__(256) void k_convert_x(const float* __restrict__ x,
                                                   unsigned short* __restrict__ o) {
  int i = (blockIdx.x * 256 + threadIdx.x) * 4;
  const int n = M_ * D_;
  const int stride = gridDim.x * 256 * 4;
  for (; i < n; i += stride) {
    const float4 v = *(const float4*)(x + i);
    ushort4 r;
    r.x = f2b(v.x); r.y = f2b(v.y); r.z = f2b(v.z); r.w = f2b(v.w);
    *(ushort4*)(o + i) = r;
  }
}

// ---------------- kernel 1: W (K x N) -> Wt bf16 (N x K), 3 matrices ----------------
__global__ __launch_bounds__(256) void k_transpose_w(const float* __restrict__ Wq,
    const float* __restrict__ Wk, const float* __restrict__ Wv,
    unsigned short* __restrict__ Wt) {
  __shared__ float t[64][65];
  const float* W = (blockIdx.z == 0) ? Wq : ((blockIdx.z == 1) ? Wk : Wv);
  unsigned short* dst = Wt + (size_t)blockIdx.z * (D_ * D_);
  const int k0 = blockIdx.x * 64, n0 = blockIdx.y * 64;
  const int tid = threadIdx.x;
#pragma unroll
  for (int i = 0; i < 16; ++i) {
    const int lin = i * 256 + tid;
    const int r = lin >> 6, c = lin & 63;
    t[r][c] = W[(size_t)(k0 + r) * D_ + n0 + c];
  }
  __syncthreads();
#pragma unroll
  for (int i = 0; i < 16; ++i) {
    const int lin = i * 256 + tid;
    const int r = lin >> 6, c = lin & 63;
    dst[(size_t)(n0 + r) * D_ + k0 + c] = f2b(t[c][r]);
  }
}

// ---------------- kernel 2: projection GEMM (m97 structure, 128x128x32) ----------------
template <int MODE>
__global__ __launch_bounds__(256) void k_proj(const unsigned short* __restrict__ X,
    const unsigned short* __restrict__ Wt,
    const float* __restrict__ bq, const float* __restrict__ bk, const float* __restrict__ bv,
    unsigned short* __restrict__ Qw, unsigned short* __restrict__ Kw,
    unsigned short* __restrict__ Vt) {
  __shared__ unsigned short xs[128 * 32];
  __shared__ unsigned short wsh[128 * 32];
  const int tid = threadIdx.x;
  const int lane = tid & 63, wv = tid >> 6;
  const int g = lane >> 4, li = lane & 15;
  const int m0 = blockIdx.x * 128;
  const int n0 = blockIdx.y * 128;
  const int wr = wv >> 1, wc = wv & 1;
  const int wtrow0 = (MODE == 0) ? n0 : (2048 + n0);

  f32x4 acc[4][4];
#pragma unroll
  for (int i = 0; i < 4; ++i)
#pragma unroll
    for (int j = 0; j < 4; ++j) acc[i][j] = (f32x4){0.f, 0.f, 0.f, 0.f};

  const int srow = wv * 32 + (lane >> 2);
  const int skel = (lane & 3) * 8;

  for (int k0 = 0; k0 < D_; k0 += 32) {
#pragma unroll
    for (int i = 0; i < 2; ++i) {
      const unsigned short* gx = X + (size_t)(m0 + srow + i * 16) * D_ + k0 + skel;
      const unsigned short* gw = Wt + (size_t)(wtrow0 + srow + i * 16) * D_ + k0 + skel;
      __builtin_amdgcn_global_load_lds(
          (const __attribute__((address_space(1))) void*)gx,
          (__attribute__((address_space(3))) void*)&xs[(wv * 32 + i * 16) * 32], 16, 0, 0);
      __builtin_amdgcn_global_load_lds(
          (const __attribute__((address_space(1))) void*)gw,
          (__attribute__((address_space(3))) void*)&wsh[(wv * 32 + i * 16) * 32], 16, 0, 0);
    }
    __syncthreads();
    bf16x8 af[4], bfr[4];
#pragma unroll
    for (int i = 0; i < 4; ++i) {
      const int ar = wr * 64 + i * 16 + li;
      const int br = wc * 64 + i * 16 + li;
      if (MODE == 0) {
        af[i]  = *(const bf16x8*)&xs[ar * 32 + g * 8];
        bfr[i] = *(const bf16x8*)&wsh[br * 32 + g * 8];
      } else {
        af[i]  = *(const bf16x8*)&wsh[ar * 32 + g * 8];
        bfr[i] = *(const bf16x8*)&xs[br * 32 + g * 8];
      }
    }
#pragma unroll
    for (int i = 0; i < 4; ++i)
#pragma unroll
      for (int j = 0; j < 4; ++j)
        acc[i][j] = __builtin_amdgcn_mfma_f32_16x16x32_bf16(af[i], bfr[j], acc[i][j], 0, 0, 0);
    __syncthreads();
  }

  if (MODE == 0) {
#pragma unroll
    for (int j = 0; j < 4; ++j) {
      const int n = n0 + wc * 64 + j * 16 + li;
      const float bias = (n < D_) ? bq[n] : bk[n - D_];
#pragma unroll
      for (int i = 0; i < 4; ++i) {
#pragma unroll
        for (int r = 0; r < 4; ++r) {
          const int m = m0 + wr * 64 + i * 16 + g * 4 + r;
          const float v = acc[i][j][r] + bias;
          const int bb = m >> 10, ss = m & 1023;
          if (n < D_) {
            Qw[((size_t)(bb * H_ + (n >> 6)) * S_ + ss) * HD_ + (n & 63)] = f2b(v * QSCALE_);
          } else {
            const int nk = n - D_;
            Kw[((size_t)(bb * H_ + (nk >> 6)) * S_ + ss) * HD_ + (nk & 63)] = f2b(v);
          }
        }
      }
    }
  } else {
#pragma unroll
    for (int i = 0; i < 4; ++i) {
#pragma unroll
      for (int r = 0; r < 4; ++r) {
        const int nv = n0 + wr * 64 + i * 16 + g * 4 + r;
        const float bias = bv[nv];
#pragma unroll
        for (int j = 0; j < 4; ++j) {
          const int m = m0 + wc * 64 + j * 16 + li;
          const int bb = m >> 10, ss = m & 1023;
          const float v = acc[i][j][r] + bias;
          Vt[((size_t)(bb * H_ + (nv >> 6)) * HD_ + (nv & 63)) * S_ + ss] = f2b(v);
        }
      }
    }
  }
}

// ---------------- kernel 3: flash attention, R7 pipeline at KVBLK=32 / 4 blocks/CU ----------------
// q-split (wave owns 16 q-rows), KVBLK=32, 32 phases. Per wave per phase: 4 DMA
// (K 1, V 1, prev 2) + 2 mask register loads = 6 VMEM -> counted vmcnt(6), two
// barriers per phase (R7-proven skeleton). LDS 37 KB -> 4 blocks/CU (16 waves):
// double the stall-overlap of the 73 KB R7 layout. PV is a single full-K
// 16x16x32 MFMA per d-block (no padded waste).
__global__ __launch_bounds__(256, 4) void k_attn(const unsigned short* __restrict__ Qw,
    const unsigned short* __restrict__ Kw, const unsigned short* __restrict__ Vt,
    const float* __restrict__ prev, const float* __restrict__ mask,
    float* __restrict__ out) {
  __shared__ unsigned short k_s[2][2048];       // 32 kv x 64 d bf16 (src-XOR-swizzled), 4 KB/buf
  __shared__ unsigned short v_s[2][2048];       // 64 d x 32 kv bf16 (linear), 4 KB/buf
  __shared__ float pm_s[2][4][2][64][4];        // prev: [buf][wave][cb][lane][4 f32], 8 KB/buf
  __shared__ unsigned short p_lds[4][16][40];   // P bounce (q-row major), 80B rows, 5 KB
  const int tid = threadIdx.x;
  const int lane = tid & 63, wv = tid >> 6;
  const int g = lane >> 4, li = lane & 15;

  const int phys = blockIdx.x + 16 * blockIdx.y;  // 0..2047
  const int xcd = phys & 7, idx = phys >> 3;
  const int qt = idx & 15;                        // consecutive same-XCD blocks: same bh
  const int bh = xcd + 8 * (idx >> 4);
  const int b = bh >> 4, h = bh & 15;
  const int q0 = qt * 64 + wv * 16;

  const float* pdma = prev + (size_t)bh * S_ * S_ + (size_t)(q0 + li) * S_ + g * 4;
  const float* mb   = mask + (size_t)b * S_ * S_ + (size_t)(q0 + li) * S_ + g * 4;
  const unsigned short* kbase = Kw + (size_t)bh * S_ * HD_;
  const unsigned short* vbase = Vt + (size_t)bh * HD_ * S_;

  // Q fragment (B-operand; col=li=q, k=g*8+e=d), pre-scaled by SCALE*LOG2E
  bf16x8 qf[2];
  {
    const unsigned short* qp = Qw + ((size_t)bh * S_ + q0 + li) * HD_ + g * 8;
    qf[0] = *(const bf16x8*)qp;
    qf[1] = *(const bf16x8*)(qp + 32);
  }

  // K DMA: 256 chunks of 16B; thread tid -> row tid>>3 (32 rows), col-chunk tid&7.
  // Source col-chunk XOR-swizzled by row&7 (rule #21); LDS dest linear.
  const int krow = tid >> 3;
  const int koff = krow * HD_ + (((tid & 7) ^ (krow & 7)) << 3);
  // V DMA: thread tid -> d-row tid>>2 (64 rows), kv-chunk tid&3; linear.
  const int voff = (tid >> 2) * S_ + ((tid & 3) << 3);

  // 4 global_load_lds + 2 mask VGPR loads per phase per wave
#define STAGE(TN, BI)                                                                      \
  {                                                                                        \
    const int sn = (TN) * 32;                                                              \
    __builtin_amdgcn_global_load_lds(                                                      \
        (const __attribute__((address_space(1))) void*)(kbase + (size_t)sn * HD_ + koff),  \
        (__attribute__((address_space(3))) void*)(&k_s[BI][0] + wv * 512), 16, 0, 0);      \
    __builtin_amdgcn_global_load_lds(                                                      \
        (const __attribute__((address_space(1))) void*)(vbase + voff + sn),                \
        (__attribute__((address_space(3))) void*)(&v_s[BI][0] + wv * 512), 16, 0, 0);      \
    __builtin_amdgcn_global_load_lds(                                                      \
        (const __attribute__((address_space(1))) void*)(pdma + sn),                        \
        (__attribute__((address_space(3))) void*)&pm_s[BI][wv][0][0][0], 16, 0, 0);        \
    __builtin_amdgcn_global_load_lds(                                                      \
        (const __attribute__((address_space(1))) void*)(pdma + sn + 16),                   \
        (__attribute__((address_space(3))) void*)&pm_s[BI][wv][1][0][0], 16, 0, 0);        \
  }

  float lrun = 0.f;
  f32x4 ctx[4];
#pragma unroll
  for (int d = 0; d < 4; ++d) ctx[d] = (f32x4){0.f, 0.f, 0.f, 0.f};

  f32x4 mA[2], mB[2];

  // prologue: stage tile 0 + mask(0)  (6 VMEM ops in flight)
  STAGE(0, 0);
  mA[0] = *(const f32x4*)(mb);
  mA[1] = *(const f32x4*)(mb + 16);

  // Phase: STAGE(t+1,NB)+mask(t+1) [6 ops] -> vmcnt(6) [t's 6 done, t+1's stay
  // in flight] -> barrier -> compute(buf PB, MCUR) -> barrier (WAR).
#define PHASE(T, PB, NB, MCUR, MNXT)                                                  \
  {                                                                                   \
    const int tn = ((T) < 31) ? (T) + 1 : 31;                                         \
    STAGE(tn, NB);                                                                    \
    MNXT[0] = *(const f32x4*)(mb + tn * 32);                                          \
    MNXT[1] = *(const f32x4*)(mb + tn * 32 + 16);                                     \
    asm volatile("s_waitcnt vmcnt(6)" ::: "memory");                                  \
    __builtin_amdgcn_s_barrier();                                                     \
    {                                                                                 \
      const unsigned short* kb = &k_s[PB][0];                                         \
      const unsigned short* vb = &v_s[PB][0];                                         \
      f32x4 sa[2];                                                                    \
      _Pragma("unroll")                                                               \
      for (int cb = 0; cb < 2; ++cb) {                                                \
        const int r = cb * 16 + li;                                                   \
        const bf16x8 k0 = *(const bf16x8*)(kb + r * 64 + ((g ^ (li & 7)) << 3));      \
        const bf16x8 k1 = *(const bf16x8*)(kb + r * 64 + (((4 + g) ^ (li & 7)) << 3)); \
        f32x4 z = (f32x4){0.f, 0.f, 0.f, 0.f};                                        \
        z      = __builtin_amdgcn_mfma_f32_16x16x32_bf16(k0, qf[0], z, 0, 0, 0);      \
        sa[cb] = __builtin_amdgcn_mfma_f32_16x16x32_bf16(k1, qf[1], z, 0, 0, 0);      \
      }                                                                               \
      _Pragma("unroll")                                                               \
      for (int cb = 0; cb < 2; ++cb) {                                                \
        const f32x4 pv = *(const f32x4*)&pm_s[PB][wv][cb][lane][0];                   \
        f32x4 pmc;                                                                    \
        pmc.x = fmaf(pv.x + MCUR[cb].x, LOG2E, -MSHIFT_);                             \
        pmc.y = fmaf(pv.y + MCUR[cb].y, LOG2E, -MSHIFT_);                             \
        pmc.z = fmaf(pv.z + MCUR[cb].z, LOG2E, -MSHIFT_);                             \
        pmc.w = fmaf(pv.w + MCUR[cb].w, LOG2E, -MSHIFT_);                             \
        const float e0 = exp2f(sa[cb][0] + pmc.x);                                    \
        const float e1 = exp2f(sa[cb][1] + pmc.y);                                    \
        const float e2 = exp2f(sa[cb][2] + pmc.z);                                    \
        const float e3 = exp2f(sa[cb][3] + pmc.w);                                    \
        lrun += (e0 + e1) + (e2 + e3);                                                \
        ushort4 pw;                                                                   \
        pw.x = f2b(e0); pw.y = f2b(e1); pw.z = f2b(e2); pw.w = f2b(e3);               \
        *(ushort4*)&p_lds[wv][li][cb * 16 + g * 4] = pw;                              \
      }                                                                               \
      const bf16x8 pf = *(const bf16x8*)&p_lds[wv][li][g * 8];                        \
      _Pragma("unroll")                                                               \
      for (int d = 0; d < 4; ++d) {                                                   \
        const bf16x8 vf = *(const bf16x8*)(vb + (d * 16 + li) * 32 + g * 8);          \
        ctx[d] = __builtin_amdgcn_mfma_f32_16x16x32_bf16(pf, vf, ctx[d], 0, 0, 0);    \
      }                                                                               \
    }                                                                                 \
    __builtin_amdgcn_s_barrier();                                                     \
  }

  for (int t = 0; t < 32; t += 2) {
    PHASE(t,     0, 1, mA, mB);
    PHASE(t + 1, 1, 0, mB, mA);
  }
#undef PHASE
#undef STAGE

  // drain the redundant tail STAGE before LDS deallocation at wave exit
  asm volatile("s_waitcnt vmcnt(0)" ::: "memory");

  // row sums: combine the 4 g-groups (lane li holds partial for q-row li)
  lrun += __shfl_xor(lrun, 16);
  lrun += __shfl_xor(lrun, 32);
#pragma unroll
  for (int j = 0; j < 4; ++j) {
    const float rs = __shfl(lrun, g * 4 + j);
    const float inv = 1.0f / rs;
    const int q = q0 + g * 4 + j;
    float* op = out + ((size_t)b * S_ + q) * D_ + h * HD_ + li;
#pragma unroll
    for (int d = 0; d < 4; ++d)
      op[d * 16] = ctx[d][j] * inv;
  }
}

extern "C" void kernel_launch(void* const* d_in, const int* in_sizes, int n_in,
                              void* d_out, int out_size, void* d_ws, size_t ws_size,
                              hipStream_t stream) {
  const float* hs   = (const float*)d_in[0];
  const float* mask = (const float*)d_in[1];
  const float* prev = (const float*)d_in[2];
  const float* Wq   = (const float*)d_in[3];
  const float* bq   = (const float*)d_in[4];
  const float* Wk   = (const float*)d_in[5];
  const float* bk   = (const float*)d_in[6];
  const float* Wv   = (const float*)d_in[7];
  const float* bv   = (const float*)d_in[8];
  float* out = (float*)d_out;

  char* ws = (char*)d_ws;
  unsigned short* Xbf = (unsigned short*)ws;                    // 16 MB
  unsigned short* Wt  = (unsigned short*)(ws + (16ull << 20));  //  6 MB
  unsigned short* Qw  = (unsigned short*)(ws + (22ull << 20));  // 16 MB
  unsigned short* Kw  = (unsigned short*)(ws + (38ull << 20));  // 16 MB
  unsigned short* Vt  = (unsigned short*)(ws + (54ull << 20));  // 16 MB  (total 70 MB)

  k_convert_x<<<2048, 256, 0, stream>>>(hs, Xbf);
  k_transpose_w<<<dim3(16, 16, 3), 256, 0, stream>>>(Wq, Wk, Wv, Wt);
  k_proj<0><<<dim3(64, 16), 256, 0, stream>>>(Xbf, Wt, bq, bk, bv, Qw, Kw, Vt);
  k_proj<1><<<dim3(64, 8),  256, 0, stream>>>(Xbf, Wt, bq, bk, bv, Qw, Kw, Vt);
  k_attn<<<dim3(16, 128), 256, 0, stream>>>(Qw, Kw, Vt, prev, mask, out);
}

// Round 13
// 291.644 us; speedup vs baseline: 1.0985x; 1.0094x over previous
//
#include <hip/hip_runtime.h>

#define B_  8
#define S_  1024
#define D_  1024
#define H_  16
#define HD_ 64
#define M_  8192           // B*S
#define LOG2E 1.44269504088896f
#define QSCALE_ (0.125f * 1.44269504088896f)   // fold scale*log2e into Q
#define MSHIFT_ 20.0f      // static softmax shift (log2 domain)

typedef __attribute__((ext_vector_type(8))) short bf16x8;
typedef __attribute__((ext_vector_type(4))) float f32x4;

__device__ __forceinline__ unsigned short f2b(float x) {
  union { float f; unsigned u; } un; un.f = x;
  unsigned r = un.u + 0x7FFFu + ((un.u >> 16) & 1u);  // RNE
  return (unsigned short)(r >> 16);
}

// ---------------- kernel 0: hidden_states f32 -> bf16 ----------------
__global__ __launch_bounds__(256) void k_convert_x(const float* __restrict__ x,
                                                   unsigned short* __restrict__ o) {
  int i = (blockIdx.x * 256 + threadIdx.x) * 4;
  const int n = M_ * D_;
  const int stride = gridDim.x * 256 * 4;
  for (; i < n; i += stride) {
    const float4 v = *(const float4*)(x + i);
    ushort4 r;
    r.x = f2b(v.x); r.y = f2b(v.y); r.z = f2b(v.z); r.w = f2b(v.w);
    *(ushort4*)(o + i) = r;
  }
}

// ---------------- kernel 1: W (K x N) -> Wt bf16 (N x K), 3 matrices ----------------
__global__ __launch_bounds__(256) void k_transpose_w(const float* __restrict__ Wq,
    const float* __restrict__ Wk, const float* __restrict__ Wv,
    unsigned short* __restrict__ Wt) {
  __shared__ float t[64][65];
  const float* W = (blockIdx.z == 0) ? Wq : ((blockIdx.z == 1) ? Wk : Wv);
  unsigned short* dst = Wt + (size_t)blockIdx.z * (D_ * D_);
  const int k0 = blockIdx.x * 64, n0 = blockIdx.y * 64;
  const int tid = threadIdx.x;
#pragma unroll
  for (int i = 0; i < 16; ++i) {
    const int lin = i * 256 + tid;
    const int r = lin >> 6, c = lin & 63;
    t[r][c] = W[(size_t)(k0 + r) * D_ + n0 + c];
  }
  __syncthreads();
#pragma unroll
  for (int i = 0; i < 16; ++i) {
    const int lin = i * 256 + tid;
    const int r = lin >> 6, c = lin & 63;
    dst[(size_t)(n0 + r) * D_ + k0 + c] = f2b(t[c][r]);
  }
}

// ---------------- kernel 2: projection GEMM (m97 structure, 128x128x32) ----------------
template <int MODE>
__global__ __launch_bounds__(256) void k_proj(const unsigned short* __restrict__ X,
    const unsigned short* __restrict__ Wt,
    const float* __restrict__ bq, const float* __restrict__ bk, const float* __restrict__ bv,
    unsigned short* __restrict__ Qw, unsigned short* __restrict__ Kw,
    unsigned short* __restrict__ Vt) {
  __shared__ unsigned short xs[128 * 32];
  __shared__ unsigned short wsh[128 * 32];
  const int tid = threadIdx.x;
  const int lane = tid & 63, wv = tid >> 6;
  const int g = lane >> 4, li = lane & 15;
  const int m0 = blockIdx.x * 128;
  const int n0 = blockIdx.y * 128;
  const int wr = wv >> 1, wc = wv & 1;
  const int wtrow0 = (MODE == 0) ? n0 : (2048 + n0);

  f32x4 acc[4][4];
#pragma unroll
  for (int i = 0; i < 4; ++i)
#pragma unroll
    for (int j = 0; j < 4; ++j) acc[i][j] = (f32x4){0.f, 0.f, 0.f, 0.f};

  const int srow = wv * 32 + (lane >> 2);
  const int skel = (lane & 3) * 8;

  for (int k0 = 0; k0 < D_; k0 += 32) {
#pragma unroll
    for (int i = 0; i < 2; ++i) {
      const unsigned short* gx = X + (size_t)(m0 + srow + i * 16) * D_ + k0 + skel;
      const unsigned short* gw = Wt + (size_t)(wtrow0 + srow + i * 16) * D_ + k0 + skel;
      __builtin_amdgcn_global_load_lds(
          (const __attribute__((address_space(1))) void*)gx,
          (__attribute__((address_space(3))) void*)&xs[(wv * 32 + i * 16) * 32], 16, 0, 0);
      __builtin_amdgcn_global_load_lds(
          (const __attribute__((address_space(1))) void*)gw,
          (__attribute__((address_space(3))) void*)&wsh[(wv * 32 + i * 16) * 32], 16, 0, 0);
    }
    __syncthreads();
    bf16x8 af[4], bfr[4];
#pragma unroll
    for (int i = 0; i < 4; ++i) {
      const int ar = wr * 64 + i * 16 + li;
      const int br = wc * 64 + i * 16 + li;
      if (MODE == 0) {
        af[i]  = *(const bf16x8*)&xs[ar * 32 + g * 8];
        bfr[i] = *(const bf16x8*)&wsh[br * 32 + g * 8];
      } else {
        af[i]  = *(const bf16x8*)&wsh[ar * 32 + g * 8];
        bfr[i] = *(const bf16x8*)&xs[br * 32 + g * 8];
      }
    }
#pragma unroll
    for (int i = 0; i < 4; ++i)
#pragma unroll
      for (int j = 0; j < 4; ++j)
        acc[i][j] = __builtin_amdgcn_mfma_f32_16x16x32_bf16(af[i], bfr[j], acc[i][j], 0, 0, 0);
    __syncthreads();
  }

  if (MODE == 0) {
#pragma unroll
    for (int j = 0; j < 4; ++j) {
      const int n = n0 + wc * 64 + j * 16 + li;
      const float bias = (n < D_) ? bq[n] : bk[n - D_];
#pragma unroll
      for (int i = 0; i < 4; ++i) {
#pragma unroll
        for (int r = 0; r < 4; ++r) {
          const int m = m0 + wr * 64 + i * 16 + g * 4 + r;
          const float v = acc[i][j][r] + bias;
          const int bb = m >> 10, ss = m & 1023;
          if (n < D_) {
            Qw[((size_t)(bb * H_ + (n >> 6)) * S_ + ss) * HD_ + (n & 63)] = f2b(v * QSCALE_);
          } else {
            const int nk = n - D_;
            Kw[((size_t)(bb * H_ + (nk >> 6)) * S_ + ss) * HD_ + (nk & 63)] = f2b(v);
          }
        }
      }
    }
  } else {
#pragma unroll
    for (int i = 0; i < 4; ++i) {
#pragma unroll
      for (int r = 0; r < 4; ++r) {
        const int nv = n0 + wr * 64 + i * 16 + g * 4 + r;
        const float bias = bv[nv];
#pragma unroll
        for (int j = 0; j < 4; ++j) {
          const int m = m0 + wc * 64 + j * 16 + li;
          const int bb = m >> 10, ss = m & 1023;
          const float v = acc[i][j][r] + bias;
          Vt[((size_t)(bb * H_ + (nv >> 6)) * HD_ + (nv & 63)) * S_ + ss] = f2b(v);
        }
      }
    }
  }
}

// ---------------- kernel 3: flash attention, m97-style drain-per-phase, 5 blocks/CU ----------------
// The GEMM-proven pattern: single-buffered LDS (21.5 KB), per phase
// {STAGE(t) DMA + mask reg loads -> __syncthreads (drain) -> compute(t) -> __syncthreads (WAR)}.
// No explicit vmcnt choreography; latency hiding comes from 5 co-resident blocks
// per CU overlapping each other's drains (m97 sustains ~22 B/cy/CU this way vs the
// ~12 B/cy/CU all counted-vmcnt variants plateaued at).
__global__ __launch_bounds__(256, 5) void k_attn(const unsigned short* __restrict__ Qw,
    const unsigned short* __restrict__ Kw, const unsigned short* __restrict__ Vt,
    const float* __restrict__ prev, const float* __restrict__ mask,
    float* __restrict__ out) {
  __shared__ unsigned short k_s[2048];          // 32 kv x 64 d bf16 (src-XOR-swizzled), 4 KB
  __shared__ unsigned short v_s[2048];          // 64 d x 32 kv bf16 (linear), 4 KB
  __shared__ float pm_s[4][2][64][4];           // prev: [wave][cb][lane][4 f32], 8 KB
  __shared__ unsigned short p_lds[4][16][40];   // P bounce (q-row major), 80B rows, 5 KB
  const int tid = threadIdx.x;
  const int lane = tid & 63, wv = tid >> 6;
  const int g = lane >> 4, li = lane & 15;

  const int phys = blockIdx.x + 16 * blockIdx.y;  // 0..2047
  const int xcd = phys & 7, idx = phys >> 3;
  const int qt = idx & 15;                        // consecutive same-XCD blocks: same bh
  const int bh = xcd + 8 * (idx >> 4);
  const int b = bh >> 4, h = bh & 15;
  const int q0 = qt * 64 + wv * 16;

  const float* pdma = prev + (size_t)bh * S_ * S_ + (size_t)(q0 + li) * S_ + g * 4;
  const float* mb   = mask + (size_t)b * S_ * S_ + (size_t)(q0 + li) * S_ + g * 4;
  const unsigned short* kbase = Kw + (size_t)bh * S_ * HD_;
  const unsigned short* vbase = Vt + (size_t)bh * HD_ * S_;

  // Q fragment (B-operand; col=li=q, k=g*8+e=d), pre-scaled by SCALE*LOG2E
  bf16x8 qf[2];
  {
    const unsigned short* qp = Qw + ((size_t)bh * S_ + q0 + li) * HD_ + g * 8;
    qf[0] = *(const bf16x8*)qp;
    qf[1] = *(const bf16x8*)(qp + 32);
  }

  // K DMA: thread tid -> row tid>>3 (32 rows), col-chunk tid&7; source col-chunk
  // XOR-swizzled by row&7 (rule #21), LDS dest linear.
  const int krow = tid >> 3;
  const int koff = krow * HD_ + (((tid & 7) ^ (krow & 7)) << 3);
  // V DMA: thread tid -> d-row tid>>2 (64 rows), kv-chunk tid&3; linear.
  const int voff = (tid >> 2) * S_ + ((tid & 3) << 3);

  float lrun = 0.f;
  f32x4 ctx[4];
#pragma unroll
  for (int d = 0; d < 4; ++d) ctx[d] = (f32x4){0.f, 0.f, 0.f, 0.f};

  for (int t = 0; t < 32; ++t) {
    const int sn = t * 32;
    // STAGE(t): 4 DMA (K, V, prev x2)
    __builtin_amdgcn_global_load_lds(
        (const __attribute__((address_space(1))) void*)(kbase + (size_t)sn * HD_ + koff),
        (__attribute__((address_space(3))) void*)(&k_s[0] + wv * 512), 16, 0, 0);
    __builtin_amdgcn_global_load_lds(
        (const __attribute__((address_space(1))) void*)(vbase + voff + sn),
        (__attribute__((address_space(3))) void*)(&v_s[0] + wv * 512), 16, 0, 0);
    __builtin_amdgcn_global_load_lds(
        (const __attribute__((address_space(1))) void*)(pdma + sn),
        (__attribute__((address_space(3))) void*)&pm_s[wv][0][0][0], 16, 0, 0);
    __builtin_amdgcn_global_load_lds(
        (const __attribute__((address_space(1))) void*)(pdma + sn + 16),
        (__attribute__((address_space(3))) void*)&pm_s[wv][1][0][0], 16, 0, 0);
    // mask(t): 2 register loads (L2/L3-resident)
    f32x4 mA0 = *(const f32x4*)(mb + sn);
    f32x4 mA1 = *(const f32x4*)(mb + sn + 16);

    __syncthreads();   // drain: tile t fully landed

    // QK swapped: D[k][q], q=li, k=4g+reg
    f32x4 sa[2];
#pragma unroll
    for (int cb = 0; cb < 2; ++cb) {
      const int r = cb * 16 + li;
      const bf16x8 k0 = *(const bf16x8*)(&k_s[0] + r * 64 + ((g ^ (li & 7)) << 3));
      const bf16x8 k1 = *(const bf16x8*)(&k_s[0] + r * 64 + (((4 + g) ^ (li & 7)) << 3));
      f32x4 z = (f32x4){0.f, 0.f, 0.f, 0.f};
      z      = __builtin_amdgcn_mfma_f32_16x16x32_bf16(k0, qf[0], z, 0, 0, 0);
      sa[cb] = __builtin_amdgcn_mfma_f32_16x16x32_bf16(k1, qf[1], z, 0, 0, 0);
    }

    // p = exp2(sa + (prev+mask)*log2e - 20); per-lane row-sum
#pragma unroll
    for (int cb = 0; cb < 2; ++cb) {
      const f32x4 pv = *(const f32x4*)&pm_s[wv][cb][lane][0];
      const f32x4 mv = (cb == 0) ? mA0 : mA1;
      f32x4 pmc;
      pmc.x = fmaf(pv.x + mv.x, LOG2E, -MSHIFT_);
      pmc.y = fmaf(pv.y + mv.y, LOG2E, -MSHIFT_);
      pmc.z = fmaf(pv.z + mv.z, LOG2E, -MSHIFT_);
      pmc.w = fmaf(pv.w + mv.w, LOG2E, -MSHIFT_);
      const float e0 = exp2f(sa[cb][0] + pmc.x);
      const float e1 = exp2f(sa[cb][1] + pmc.y);
      const float e2 = exp2f(sa[cb][2] + pmc.z);
      const float e3 = exp2f(sa[cb][3] + pmc.w);
      lrun += (e0 + e1) + (e2 + e3);
      ushort4 pw;
      pw.x = f2b(e0); pw.y = f2b(e1); pw.z = f2b(e2); pw.w = f2b(e3);
      *(ushort4*)&p_lds[wv][li][cb * 16 + g * 4] = pw;
    }

    // P (A-layout) from per-wave bounce; single full-K 16x16x32 PV per d-block
    const bf16x8 pf = *(const bf16x8*)&p_lds[wv][li][g * 8];
#pragma unroll
    for (int d = 0; d < 4; ++d) {
      const bf16x8 vf = *(const bf16x8*)(&v_s[0] + (d * 16 + li) * 32 + g * 8);
      ctx[d] = __builtin_amdgcn_mfma_f32_16x16x32_bf16(pf, vf, ctx[d], 0, 0, 0);
    }

    __syncthreads();   // WAR: next phase's STAGE may overwrite
  }

  // row sums: combine the 4 g-groups (lane li holds partial for q-row li)
  lrun += __shfl_xor(lrun, 16);
  lrun += __shfl_xor(lrun, 32);
#pragma unroll
  for (int j = 0; j < 4; ++j) {
    const float rs = __shfl(lrun, g * 4 + j);
    const float inv = 1.0f / rs;
    const int q = q0 + g * 4 + j;
    float* op = out + ((size_t)b * S_ + q) * D_ + h * HD_ + li;
#pragma unroll
    for (int d = 0; d < 4; ++d)
      op[d * 16] = ctx[d][j] * inv;
  }
}

extern "C" void kernel_launch(void* const* d_in, const int* in_sizes, int n_in,
                              void* d_out, int out_size, void* d_ws, size_t ws_size,
                              hipStream_t stream) {
  const float* hs   = (const float*)d_in[0];
  const float* mask = (const float*)d_in[1];
  const float* prev = (const float*)d_in[2];
  const float* Wq   = (const float*)d_in[3];
  const float* bq   = (const float*)d_in[4];
  const float* Wk   = (const float*)d_in[5];
  const float* bk   = (const float*)d_in[6];
  const float* Wv   = (const float*)d_in[7];
  const float* bv   = (const float*)d_in[8];
  float* out = (float*)d_out;

  char* ws = (char*)d_ws;
  unsigned short* Xbf = (unsigned short*)ws;                    // 16 MB
  unsigned short* Wt  = (unsigned short*)(ws + (16ull << 20));  //  6 MB
  unsigned short* Qw  = (unsigned short*)(ws + (22ull << 20));  // 16 MB
  unsigned short* Kw  = (unsigned short*)(ws + (38ull << 20));  // 16 MB
  unsigned short* Vt  = (unsigned short*)(ws + (54ull << 20));  // 16 MB  (total 70 MB)

  k_convert_x<<<2048, 256, 0, stream>>>(hs, Xbf);
  k_transpose_w<<<dim3(16, 16, 3), 256, 0, stream>>>(Wq, Wk, Wv, Wt);
  k_proj<0><<<dim3(64, 16), 256, 0, stream>>>(Xbf, Wt, bq, bk, bv, Qw, Kw, Vt);
  k_proj<1><<<dim3(64, 8),  256, 0, stream>>>(Xbf, Wt, bq, bk, bv, Qw, Kw, Vt);
  k_attn<<<dim3(16, 128), 256, 0, stream>>>(Qw, Kw, Vt, prev, mask, out);
}

// Round 14
// 274.204 us; speedup vs baseline: 1.1683x; 1.0636x over previous
//
#include <hip/hip_runtime.h>

#define B_  8
#define S_  1024
#define D_  1024
#define H_  16
#define HD_ 64
#define M_  8192           // B*S
#define LOG2E 1.44269504088896f
#define QSCALE_ (0.125f * 1.44269504088896f)   // fold scale*log2e into Q
#define MSHIFT_ 20.0f      // static softmax shift (log2 domain)

typedef __attribute__((ext_vector_type(8))) short bf16x8;
typedef __attribute__((ext_vector_type(4))) float f32x4;

__device__ __forceinline__ unsigned short f2b(float x) {
  union { float f; unsigned u; } un; un.f = x;
  unsigned r = un.u + 0x7FFFu + ((un.u >> 16) & 1u);  // RNE
  return (unsigned short)(r >> 16);
}

// ---------------- kernel 0: hidden_states f32 -> bf16 ----------------
__global__ __launch_bounds__(256) void k_convert_x(const float* __restrict__ x,
                                                   unsigned short* __restrict__ o) {
  int i = (blockIdx.x * 256 + threadIdx.x) * 4;
  const int n = M_ * D_;
  const int stride = gridDim.x * 256 * 4;
  for (; i < n; i += stride) {
    const float4 v = *(const float4*)(x + i);
    ushort4 r;
    r.x = f2b(v.x); r.y = f2b(v.y); r.z = f2b(v.z); r.w = f2b(v.w);
    *(ushort4*)(o + i) = r;
  }
}

// ---------------- kernel 1: W (K x N) -> Wt bf16 (N x K), 3 matrices ----------------
__global__ __launch_bounds__(256) void k_transpose_w(const float* __restrict__ Wq,
    const float* __restrict__ Wk, const float* __restrict__ Wv,
    unsigned short* __restrict__ Wt) {
  __shared__ float t[64][65];
  const float* W = (blockIdx.z == 0) ? Wq : ((blockIdx.z == 1) ? Wk : Wv);
  unsigned short* dst = Wt + (size_t)blockIdx.z * (D_ * D_);
  const int k0 = blockIdx.x * 64, n0 = blockIdx.y * 64;
  const int tid = threadIdx.x;
#pragma unroll
  for (int i = 0; i < 16; ++i) {
    const int lin = i * 256 + tid;
    const int r = lin >> 6, c = lin & 63;
    t[r][c] = W[(size_t)(k0 + r) * D_ + n0 + c];
  }
  __syncthreads();
#pragma unroll
  for (int i = 0; i < 16; ++i) {
    const int lin = i * 256 + tid;
    const int r = lin >> 6, c = lin & 63;
    dst[(size_t)(n0 + r) * D_ + k0 + c] = f2b(t[c][r]);
  }
}

// ---------------- kernel 2: projection GEMM (m97 structure, 128x128x32) ----------------
template <int MODE>
__global__ __launch_bounds__(256) void k_proj(const unsigned short* __restrict__ X,
    const unsigned short* __restrict__ Wt,
    const float* __restrict__ bq, const float* __restrict__ bk, const float* __restrict__ bv,
    unsigned short* __restrict__ Qw, unsigned short* __restrict__ Kw,
    unsigned short* __restrict__ Vt) {
  __shared__ unsigned short xs[128 * 32];
  __shared__ unsigned short wsh[128 * 32];
  const int tid = threadIdx.x;
  const int lane = tid & 63, wv = tid >> 6;
  const int g = lane >> 4, li = lane & 15;
  const int m0 = blockIdx.x * 128;
  const int n0 = blockIdx.y * 128;
  const int wr = wv >> 1, wc = wv & 1;
  const int wtrow0 = (MODE == 0) ? n0 : (2048 + n0);

  f32x4 acc[4][4];
#pragma unroll
  for (int i = 0; i < 4; ++i)
#pragma unroll
    for (int j = 0; j < 4; ++j) acc[i][j] = (f32x4){0.f, 0.f, 0.f, 0.f};

  const int srow = wv * 32 + (lane >> 2);
  const int skel = (lane & 3) * 8;

  for (int k0 = 0; k0 < D_; k0 += 32) {
#pragma unroll
    for (int i = 0; i < 2; ++i) {
      const unsigned short* gx = X + (size_t)(m0 + srow + i * 16) * D_ + k0 + skel;
      const unsigned short* gw = Wt + (size_t)(wtrow0 + srow + i * 16) * D_ + k0 + skel;
      __builtin_amdgcn_global_load_lds(
          (const __attribute__((address_space(1))) void*)gx,
          (__attribute__((address_space(3))) void*)&xs[(wv * 32 + i * 16) * 32], 16, 0, 0);
      __builtin_amdgcn_global_load_lds(
          (const __attribute__((address_space(1))) void*)gw,
          (__attribute__((address_space(3))) void*)&wsh[(wv * 32 + i * 16) * 32], 16, 0, 0);
    }
    __syncthreads();
    bf16x8 af[4], bfr[4];
#pragma unroll
    for (int i = 0; i < 4; ++i) {
      const int ar = wr * 64 + i * 16 + li;
      const int br = wc * 64 + i * 16 + li;
      if (MODE == 0) {
        af[i]  = *(const bf16x8*)&xs[ar * 32 + g * 8];
        bfr[i] = *(const bf16x8*)&wsh[br * 32 + g * 8];
      } else {
        af[i]  = *(const bf16x8*)&wsh[ar * 32 + g * 8];
        bfr[i] = *(const bf16x8*)&xs[br * 32 + g * 8];
      }
    }
#pragma unroll
    for (int i = 0; i < 4; ++i)
#pragma unroll
      for (int j = 0; j < 4; ++j)
        acc[i][j] = __builtin_amdgcn_mfma_f32_16x16x32_bf16(af[i], bfr[j], acc[i][j], 0, 0, 0);
    __syncthreads();
  }

  if (MODE == 0) {
#pragma unroll
    for (int j = 0; j < 4; ++j) {
      const int n = n0 + wc * 64 + j * 16 + li;
      const float bias = (n < D_) ? bq[n] : bk[n - D_];
#pragma unroll
      for (int i = 0; i < 4; ++i) {
#pragma unroll
        for (int r = 0; r < 4; ++r) {
          const int m = m0 + wr * 64 + i * 16 + g * 4 + r;
          const float v = acc[i][j][r] + bias;
          const int bb = m >> 10, ss = m & 1023;
          if (n < D_) {
            Qw[((size_t)(bb * H_ + (n >> 6)) * S_ + ss) * HD_ + (n & 63)] = f2b(v * QSCALE_);
          } else {
            const int nk = n - D_;
            Kw[((size_t)(bb * H_ + (nk >> 6)) * S_ + ss) * HD_ + (nk & 63)] = f2b(v);
          }
        }
      }
    }
  } else {
#pragma unroll
    for (int i = 0; i < 4; ++i) {
#pragma unroll
      for (int r = 0; r < 4; ++r) {
        const int nv = n0 + wr * 64 + i * 16 + g * 4 + r;
        const float bias = bv[nv];
#pragma unroll
        for (int j = 0; j < 4; ++j) {
          const int m = m0 + wc * 64 + j * 16 + li;
          const int bb = m >> 10, ss = m & 1023;
          const float v = acc[i][j][r] + bias;
          Vt[((size_t)(bb * H_ + (nv >> 6)) * HD_ + (nv & 63)) * S_ + ss] = f2b(v);
        }
      }
    }
  }
}

// ---------------- kernel 3: flash attention, KVBLK=128 contiguous-DMA tiles ----------------
// Hypothesis under test: scattered 64B-line DMA footprints cap staging at ~12 B/cy/CU.
// KVBLK=128 makes per-DMA footprints contiguous runs: K 1KB fully contiguous,
// prev 2x512B, V 4x256B. m97-style drain-per-phase loop (8 phases), single buffer,
// all LDS tiles source-XOR-swizzled (key=row&7 on 16B chunks) with matching read XOR.
__global__ __launch_bounds__(256, 2) void k_attn(const unsigned short* __restrict__ Qw,
    const unsigned short* __restrict__ Kw, const unsigned short* __restrict__ Vt,
    const float* __restrict__ prev, const float* __restrict__ mask,
    float* __restrict__ out) {
  __shared__ unsigned short k_s[128 * 64];      // [kv][d] bf16, 16 KB, swizzled chunks
  __shared__ unsigned short v_s[64 * 128];      // [d][kv] bf16, 16 KB, swizzled chunks
  __shared__ float pm_s[4][16][128];            // prev: [wave][qrow][kv] f32, 32 KB, swizzled
  __shared__ unsigned short p_lds[4][16][128];  // P bounce: [wave][qrow][kv] bf16, 16 KB, swizzled
  const int tid = threadIdx.x;
  const int lane = tid & 63, wv = tid >> 6;
  const int g = lane >> 4, li = lane & 15;

  const int phys = blockIdx.x + 16 * blockIdx.y;  // 0..2047
  const int xcd = phys & 7, idx = phys >> 3;
  const int qt = idx & 15;                        // consecutive same-XCD blocks: same bh
  const int bh = xcd + 8 * (idx >> 4);
  const int b = bh >> 4, h = bh & 15;
  const int q0 = qt * 64 + wv * 16;               // this wave's 16 q-rows

  const unsigned short* kbase = Kw + (size_t)bh * S_ * HD_;
  const unsigned short* vbase = Vt + (size_t)bh * HD_ * S_;
  const float* pbase = prev + (size_t)bh * S_ * S_ + (size_t)q0 * S_;  // wave's q-slice
  const float* mb    = mask + (size_t)b * S_ * S_ + (size_t)(q0 + li) * S_ + g * 4;

  // Q fragment (B-operand; col=li=q, k=g*8+e=d), pre-scaled by SCALE*LOG2E
  bf16x8 qf[2];
  {
    const unsigned short* qp = Qw + ((size_t)bh * S_ + q0 + li) * HD_ + g * 8;
    qf[0] = *(const bf16x8*)qp;
    qf[1] = *(const bf16x8*)(qp + 32);
  }

  float lrun = 0.f;
  f32x4 ctx[4];
#pragma unroll
  for (int d = 0; d < 4; ++d) ctx[d] = (f32x4){0.f, 0.f, 0.f, 0.f};

  for (int t = 0; t < 8; ++t) {
    const int sn = t * 128;

    // ---- STAGE tile t (16 DMA/wave, contiguous runs, src-XOR-swizzled) ----
    // K: 4 DMA x (8 consecutive kv-rows x 128B = 1KB contiguous)
#pragma unroll
    for (int i = 0; i < 4; ++i) {
      const int rloc = (lane >> 3);                       // 0..7 within the 8-row group
      const int row = wv * 32 + i * 8 + rloc;             // kv row in tile
      const int csw = ((lane & 7) ^ (rloc & 7)) << 3;     // swizzled 16B chunk (8/row)
      __builtin_amdgcn_global_load_lds(
          (const __attribute__((address_space(1))) void*)(kbase + (size_t)(sn + row) * HD_ + csw),
          (__attribute__((address_space(3))) void*)(&k_s[0] + (wv * 32 + i * 8) * 64), 16, 0, 0);
    }
    // V: 4 DMA x (4 d-rows x 256B runs)
#pragma unroll
    for (int i = 0; i < 4; ++i) {
      const int rloc = (lane >> 4);                       // 0..3
      const int drow = wv * 16 + i * 4 + rloc;
      const int csw = ((lane & 15) ^ (drow & 7)) << 3;    // 16 chunks/row
      __builtin_amdgcn_global_load_lds(
          (const __attribute__((address_space(1))) void*)(vbase + (size_t)drow * S_ + sn + csw),
          (__attribute__((address_space(3))) void*)(&v_s[0] + (wv * 16 + i * 4) * 128), 16, 0, 0);
    }
    // prev: 8 DMA x (2 q-rows x 512B runs) into this wave's private slice
#pragma unroll
    for (int i = 0; i < 8; ++i) {
      const int rloc = i * 2 + (lane >> 5);               // 0..15 q-row within wave slice
      const int csw = ((lane & 31) ^ (rloc & 7)) << 2;    // 32 chunks/row, f32 units x4
      __builtin_amdgcn_global_load_lds(
          (const __attribute__((address_space(1))) void*)(pbase + (size_t)rloc * S_ + sn + csw),
          (__attribute__((address_space(3))) void*)(&pm_s[wv][i * 2][0]), 16, 0, 0);
    }
    // mask: 8 f32x4 register loads (L2/L3-resident)
    f32x4 mA[8];
#pragma unroll
    for (int cb = 0; cb < 8; ++cb) mA[cb] = *(const f32x4*)(mb + sn + cb * 16);

    __syncthreads();   // drain: tile t fully landed

    // ---- QK + softmax, per cb (8 cbs of 16 kv) ----
#pragma unroll
    for (int cb = 0; cb < 8; ++cb) {
      const int row = cb * 16 + li;
      const bf16x8 k0 = *(const bf16x8*)(&k_s[0] + row * 64 + ((g ^ (li & 7)) << 3));
      const bf16x8 k1 = *(const bf16x8*)(&k_s[0] + row * 64 + (((4 + g) ^ (li & 7)) << 3));
      f32x4 z = (f32x4){0.f, 0.f, 0.f, 0.f};
      z = __builtin_amdgcn_mfma_f32_16x16x32_bf16(k0, qf[0], z, 0, 0, 0);
      const f32x4 sa = __builtin_amdgcn_mfma_f32_16x16x32_bf16(k1, qf[1], z, 0, 0, 0);
      // prev read (swizzled): chunk (cb*4+g) ^ (li&7), 4 f32
      const int pchk = ((cb * 4 + g) ^ (li & 7)) << 2;
      const f32x4 pv = *(const f32x4*)&pm_s[wv][li][pchk];
      f32x4 pmc;
      pmc.x = fmaf(pv.x + mA[cb].x, LOG2E, -MSHIFT_);
      pmc.y = fmaf(pv.y + mA[cb].y, LOG2E, -MSHIFT_);
      pmc.z = fmaf(pv.z + mA[cb].z, LOG2E, -MSHIFT_);
      pmc.w = fmaf(pv.w + mA[cb].w, LOG2E, -MSHIFT_);
      const float e0 = exp2f(sa[0] + pmc.x);
      const float e1 = exp2f(sa[1] + pmc.y);
      const float e2 = exp2f(sa[2] + pmc.z);
      const float e3 = exp2f(sa[3] + pmc.w);
      lrun += (e0 + e1) + (e2 + e3);
      ushort4 pw;
      pw.x = f2b(e0); pw.y = f2b(e1); pw.z = f2b(e2); pw.w = f2b(e3);
      // P write: 8B half of 16B chunk (cb*2 + (g>>1)) ^ (li&7), half g&1
      const int wchk = ((cb * 2 + (g >> 1)) ^ (li & 7)) << 3;
      *(ushort4*)(&p_lds[wv][li][0] + wchk + (g & 1) * 4) = pw;
    }

    // ---- PV: 4 kv-chunks of 32, 4 d-blocks ----
#pragma unroll
    for (int c = 0; c < 4; ++c) {
      const int pchk = ((c * 4 + g) ^ (li & 7)) << 3;
      const bf16x8 pf = *(const bf16x8*)(&p_lds[wv][li][0] + pchk);
#pragma unroll
      for (int d = 0; d < 4; ++d) {
        const int vrow = d * 16 + li;
        const int vchk = ((c * 4 + g) ^ (li & 7)) << 3;
        const bf16x8 vf = *(const bf16x8*)(&v_s[0] + vrow * 128 + vchk);
        ctx[d] = __builtin_amdgcn_mfma_f32_16x16x32_bf16(pf, vf, ctx[d], 0, 0, 0);
      }
    }

    __syncthreads();   // WAR: next phase's STAGE may overwrite
  }

  // row sums: combine the 4 g-groups (lane li holds partial for q-row li)
  lrun += __shfl_xor(lrun, 16);
  lrun += __shfl_xor(lrun, 32);
#pragma unroll
  for (int j = 0; j < 4; ++j) {
    const float rs = __shfl(lrun, g * 4 + j);
    const float inv = 1.0f / rs;
    const int q = q0 + g * 4 + j;
    float* op = out + ((size_t)b * S_ + q) * D_ + h * HD_ + li;
#pragma unroll
    for (int d = 0; d < 4; ++d)
      op[d * 16] = ctx[d][j] * inv;
  }
}

extern "C" void kernel_launch(void* const* d_in, const int* in_sizes, int n_in,
                              void* d_out, int out_size, void* d_ws, size_t ws_size,
                              hipStream_t stream) {
  const float* hs   = (const float*)d_in[0];
  const float* mask = (const float*)d_in[1];
  const float* prev = (const float*)d_in[2];
  const float* Wq   = (const float*)d_in[3];
  const float* bq   = (const float*)d_in[4];
  const float* Wk   = (const float*)d_in[5];
  const float* bk   = (const float*)d_in[6];
  const float* Wv   = (const float*)d_in[7];
  const float* bv   = (const float*)d_in[8];
  float* out = (float*)d_out;

  char* ws = (char*)d_ws;
  unsigned short* Xbf = (unsigned short*)ws;                    // 16 MB
  unsigned short* Wt  = (unsigned short*)(ws + (16ull << 20));  //  6 MB
  unsigned short* Qw  = (unsigned short*)(ws + (22ull << 20));  // 16 MB
  unsigned short* Kw  = (unsigned short*)(ws + (38ull << 20));  // 16 MB
  unsigned short* Vt  = (unsigned short*)(ws + (54ull << 20));  // 16 MB  (total 70 MB)

  k_convert_x<<<2048, 256, 0, stream>>>(hs, Xbf);
  k_transpose_w<<<dim3(16, 16, 3), 256, 0, stream>>>(Wq, Wk, Wv, Wt);
  k_proj<0><<<dim3(64, 16), 256, 0, stream>>>(Xbf, Wt, bq, bk, bv, Qw, Kw, Vt);
  k_proj<1><<<dim3(64, 8),  256, 0, stream>>>(Xbf, Wt, bq, bk, bv, Qw, Kw, Vt);
  k_attn<<<dim3(16, 128), 256, 0, stream>>>(Qw, Kw, Vt, prev, mask, out);
}

// Round 15
// 267.819 us; speedup vs baseline: 1.1962x; 1.0238x over previous
//
#include <hip/hip_runtime.h>

#define B_  8
#define S_  1024
#define D_  1024
#define H_  16
#define HD_ 64
#define M_  8192           // B*S
#define LOG2E 1.44269504088896f
#define QSCALE_ (0.125f * 1.44269504088896f)   // fold scale*log2e into Q
#define MSHIFT_ 20.0f      // static softmax shift (log2 domain)

typedef __attribute__((ext_vector_type(8))) short bf16x8;
typedef __attribute__((ext_vector_type(4))) float f32x4;

__device__ __forceinline__ unsigned short f2b(float x) {
  union { float f; unsigned u; } un; un.f = x;
  unsigned r = un.u + 0x7FFFu + ((un.u >> 16) & 1u);  // RNE
  return (unsigned short)(r >> 16);
}

// ---------------- kernel 0: hidden_states f32 -> bf16 ----------------
__global__ __launch_bounds__(256) void k_convert_x(const float* __restrict__ x,
                                                   unsigned short* __restrict__ o) {
  int i = (blockIdx.x * 256 + threadIdx.x) * 4;
  const int n = M_ * D_;
  const int stride = gridDim.x * 256 * 4;
  for (; i < n; i += stride) {
    const float4 v = *(const float4*)(x + i);
    ushort4 r;
    r.x = f2b(v.x); r.y = f2b(v.y); r.z = f2b(v.z); r.w = f2b(v.w);
    *(ushort4*)(o + i) = r;
  }
}

// ---------------- kernel 1: W (K x N) -> Wt bf16 (N x K), 3 matrices ----------------
__global__ __launch_bounds__(256) void k_transpose_w(const float* __restrict__ Wq,
    const float* __restrict__ Wk, const float* __restrict__ Wv,
    unsigned short* __restrict__ Wt) {
  __shared__ float t[64][65];
  const float* W = (blockIdx.z == 0) ? Wq : ((blockIdx.z == 1) ? Wk : Wv);
  unsigned short* dst = Wt + (size_t)blockIdx.z * (D_ * D_);
  const int k0 = blockIdx.x * 64, n0 = blockIdx.y * 64;
  const int tid = threadIdx.x;
#pragma unroll
  for (int i = 0; i < 16; ++i) {
    const int lin = i * 256 + tid;
    const int r = lin >> 6, c = lin & 63;
    t[r][c] = W[(size_t)(k0 + r) * D_ + n0 + c];
  }
  __syncthreads();
#pragma unroll
  for (int i = 0; i < 16; ++i) {
    const int lin = i * 256 + tid;
    const int r = lin >> 6, c = lin & 63;
    dst[(size_t)(n0 + r) * D_ + k0 + c] = f2b(t[c][r]);
  }
}

// ---------------- kernel 2: merged projection GEMM (m97 structure, 128x128x32) ----------------
// blockIdx.y < 16: Q,K tiles (mode 0). blockIdx.y in [16,24): V^T tiles (mode 1).
__global__ __launch_bounds__(256) void k_proj(const unsigned short* __restrict__ X,
    const unsigned short* __restrict__ Wt,
    const float* __restrict__ bq, const float* __restrict__ bk, const float* __restrict__ bv,
    unsigned short* __restrict__ Qw, unsigned short* __restrict__ Kw,
    unsigned short* __restrict__ Vt) {
  __shared__ unsigned short xs[128 * 32];
  __shared__ unsigned short wsh[128 * 32];
  const int tid = threadIdx.x;
  const int lane = tid & 63, wv = tid >> 6;
  const int g = lane >> 4, li = lane & 15;
  const int m0 = blockIdx.x * 128;
  const int mode = (blockIdx.y >= 16);
  const int n0 = (mode ? (blockIdx.y - 16) : blockIdx.y) * 128;
  const int wr = wv >> 1, wc = wv & 1;
  const int wtrow0 = mode ? (2048 + n0) : n0;

  f32x4 acc[4][4];
#pragma unroll
  for (int i = 0; i < 4; ++i)
#pragma unroll
    for (int j = 0; j < 4; ++j) acc[i][j] = (f32x4){0.f, 0.f, 0.f, 0.f};

  const int srow = wv * 32 + (lane >> 2);
  const int skel = (lane & 3) * 8;

  for (int k0 = 0; k0 < D_; k0 += 32) {
#pragma unroll
    for (int i = 0; i < 2; ++i) {
      const unsigned short* gx = X + (size_t)(m0 + srow + i * 16) * D_ + k0 + skel;
      const unsigned short* gw = Wt + (size_t)(wtrow0 + srow + i * 16) * D_ + k0 + skel;
      __builtin_amdgcn_global_load_lds(
          (const __attribute__((address_space(1))) void*)gx,
          (__attribute__((address_space(3))) void*)&xs[(wv * 32 + i * 16) * 32], 16, 0, 0);
      __builtin_amdgcn_global_load_lds(
          (const __attribute__((address_space(1))) void*)gw,
          (__attribute__((address_space(3))) void*)&wsh[(wv * 32 + i * 16) * 32], 16, 0, 0);
    }
    __syncthreads();
    bf16x8 af[4], bfr[4];
#pragma unroll
    for (int i = 0; i < 4; ++i) {
      const int ar = wr * 64 + i * 16 + li;
      const int br = wc * 64 + i * 16 + li;
      if (!mode) {
        af[i]  = *(const bf16x8*)&xs[ar * 32 + g * 8];
        bfr[i] = *(const bf16x8*)&wsh[br * 32 + g * 8];
      } else {
        af[i]  = *(const bf16x8*)&wsh[ar * 32 + g * 8];
        bfr[i] = *(const bf16x8*)&xs[br * 32 + g * 8];
      }
    }
#pragma unroll
    for (int i = 0; i < 4; ++i)
#pragma unroll
      for (int j = 0; j < 4; ++j)
        acc[i][j] = __builtin_amdgcn_mfma_f32_16x16x32_bf16(af[i], bfr[j], acc[i][j], 0, 0, 0);
    __syncthreads();
  }

  if (!mode) {
#pragma unroll
    for (int j = 0; j < 4; ++j) {
      const int n = n0 + wc * 64 + j * 16 + li;
      const float bias = (n < D_) ? bq[n] : bk[n - D_];
#pragma unroll
      for (int i = 0; i < 4; ++i) {
#pragma unroll
        for (int r = 0; r < 4; ++r) {
          const int m = m0 + wr * 64 + i * 16 + g * 4 + r;
          const float v = acc[i][j][r] + bias;
          const int bb = m >> 10, ss = m & 1023;
          if (n < D_) {
            Qw[((size_t)(bb * H_ + (n >> 6)) * S_ + ss) * HD_ + (n & 63)] = f2b(v * QSCALE_);
          } else {
            const int nk = n - D_;
            Kw[((size_t)(bb * H_ + (nk >> 6)) * S_ + ss) * HD_ + (nk & 63)] = f2b(v);
          }
        }
      }
    }
  } else {
#pragma unroll
    for (int i = 0; i < 4; ++i) {
#pragma unroll
      for (int r = 0; r < 4; ++r) {
        const int nv = n0 + wr * 64 + i * 16 + g * 4 + r;
        const float bias = bv[nv];
#pragma unroll
        for (int j = 0; j < 4; ++j) {
          const int m = m0 + wc * 64 + j * 16 + li;
          const int bb = m >> 10, ss = m & 1023;
          const float v = acc[i][j][r] + bias;
          Vt[((size_t)(bb * H_ + (nv >> 6)) * HD_ + (nv & 63)) * S_ + ss] = f2b(v);
        }
      }
    }
  }
}

// ---------------- kernel 3: flash attention, R7 dbuf/vmcnt pipeline + contiguous DMA ----------------
// KVBLK=64, 16 phases, counted vmcnt(12), 2 barriers/phase (R7-proven). DMA footprints
// made contiguous (R14's win): K/V = 1KB over 8 consecutive rows (XOR-permuted within
// rows), prev = 4 rows x 256B runs into a row-major XOR-swizzled pm layout
// (bank-uniform on the exp read). Compute section byte-identical to R7.
__global__ __launch_bounds__(256, 2) void k_attn(const unsigned short* __restrict__ Qw,
    const unsigned short* __restrict__ Kw, const unsigned short* __restrict__ Vt,
    const float* __restrict__ prev, const float* __restrict__ mask,
    float* __restrict__ out) {
  __shared__ unsigned short k_s[2][4096];       // [buf] 64 kv x 64 d, swizzled chunks, 8 KB/buf
  __shared__ unsigned short v_s[2][4096];       // [buf] 64 d x 64 kv, swizzled chunks, 8 KB/buf
  __shared__ float pm_s[2][4][1024];            // [buf][wave] 16 q x 64 kv f32, swizzled, 16 KB/buf
  __shared__ unsigned short p_lds[4][16][72];   // P bounce (q-row major), 144B rows, 9 KB
  const int tid = threadIdx.x;
  const int lane = tid & 63, wv = tid >> 6;
  const int g = lane >> 4, li = lane & 15;

  const int phys = blockIdx.x + 16 * blockIdx.y;  // 0..2047
  const int xcd = phys & 7, idx = phys >> 3;
  const int qt = idx & 15;                        // consecutive same-XCD blocks: same bh
  const int bh = xcd + 8 * (idx >> 4);
  const int b = bh >> 4, h = bh & 15;
  const int q0 = qt * 64 + wv * 16;

  const unsigned short* kbase = Kw + (size_t)bh * S_ * HD_;
  const unsigned short* vbase = Vt + (size_t)bh * HD_ * S_;
  const float* pbase = prev + (size_t)bh * S_ * S_ + (size_t)q0 * S_;  // wave's q-slice
  const float* mb    = mask + (size_t)b * S_ * S_ + (size_t)(q0 + li) * S_ + g * 4;

  // Q fragment (B-operand; col=li=q, k=g*8+e=d), pre-scaled by SCALE*LOG2E
  bf16x8 qf[2];
  {
    const unsigned short* qp = Qw + ((size_t)bh * S_ + q0 + li) * HD_ + g * 8;
    qf[0] = *(const bf16x8*)qp;
    qf[1] = *(const bf16x8*)(qp + 32);
  }

  // K/V DMA: per DMA 8 consecutive rows x 128B (1KB contiguous); lane l -> row
  // group rloc8 = l>>3, chunk (l&7)^rloc8 (XOR permutes within the row: contiguity kept).
  const int rloc8 = lane >> 3;
  const int csw8  = (((lane & 7) ^ rloc8) << 3);   // ushort offset of swizzled 16B chunk
  // prev DMA: per DMA 4 rows x 256B; lane l -> row i*4 + (l>>4), chunk (l&15)^(row&7).
  const int prow4 = lane >> 4;
  const int pchnk = lane & 15;

  // 8 global_load_lds + 4 mask VGPR loads per phase per wave = 12 VMEM
#define STAGE(TN, BI)                                                                      \
  {                                                                                        \
    const int sn = (TN) * 64;                                                              \
    _Pragma("unroll")                                                                      \
    for (int i = 0; i < 2; ++i) {                                                          \
      const int row = wv * 16 + i * 8 + rloc8;                                             \
      __builtin_amdgcn_global_load_lds(                                                    \
          (const __attribute__((address_space(1))) void*)(kbase + (size_t)(sn + row) * HD_ + csw8), \
          (__attribute__((address_space(3))) void*)(&k_s[BI][0] + (wv * 16 + i * 8) * 64), 16, 0, 0); \
      __builtin_amdgcn_global_load_lds(                                                    \
          (const __attribute__((address_space(1))) void*)(vbase + (size_t)row * S_ + sn + csw8), \
          (__attribute__((address_space(3))) void*)(&v_s[BI][0] + (wv * 16 + i * 8) * 64), 16, 0, 0); \
    }                                                                                      \
    _Pragma("unroll")                                                                      \
    for (int i = 0; i < 4; ++i) {                                                          \
      const int row = i * 4 + prow4;                                                       \
      __builtin_amdgcn_global_load_lds(                                                    \
          (const __attribute__((address_space(1))) void*)(pbase + (size_t)row * S_ + sn + ((pchnk ^ (row & 7)) << 2)), \
          (__attribute__((address_space(3))) void*)(&pm_s[BI][wv][i * 256]), 16, 0, 0);    \
    }                                                                                      \
  }

  float lrun = 0.f;
  f32x4 ctx[4];
#pragma unroll
  for (int d = 0; d < 4; ++d) ctx[d] = (f32x4){0.f, 0.f, 0.f, 0.f};

  f32x4 mA[4], mB[4];

  // prologue: stage tile 0 + mask(0)  (12 VMEM ops, not waited here)
  STAGE(0, 0);
#pragma unroll
  for (int cb = 0; cb < 4; ++cb) mA[cb] = *(const f32x4*)(mb + cb * 16);

  // Phase: STAGE(t+1,NB) + mask(t+1) [12 ops] -> vmcnt(12) [prev phase's 12 done,
  // current 12 stay in flight] -> barrier -> compute(buf PB, MCUR) -> barrier (WAR).
#define PHASE(T, PB, NB, MCUR, MNXT)                                                  \
  {                                                                                   \
    const int tn = ((T) < 15) ? (T) + 1 : 15;                                         \
    STAGE(tn, NB);                                                                    \
    _Pragma("unroll")                                                                 \
    for (int cb = 0; cb < 4; ++cb)                                                    \
      MNXT[cb] = *(const f32x4*)(mb + tn * 64 + cb * 16);                             \
    asm volatile("s_waitcnt vmcnt(12)" ::: "memory");                                 \
    __builtin_amdgcn_s_barrier();                                                     \
    {                                                                                 \
      const unsigned short* kb = &k_s[PB][0];                                         \
      const unsigned short* vb = &v_s[PB][0];                                         \
      const float* pmw = &pm_s[PB][wv][0];                                            \
      f32x4 sa[4];                                                                    \
      _Pragma("unroll")                                                               \
      for (int cb = 0; cb < 4; ++cb) {                                                \
        const int r = cb * 16 + li;                                                   \
        const bf16x8 k0 = *(const bf16x8*)(kb + r * 64 + ((g ^ (li & 7)) << 3));      \
        const bf16x8 k1 = *(const bf16x8*)(kb + r * 64 + (((4 + g) ^ (li & 7)) << 3)); \
        f32x4 z = (f32x4){0.f, 0.f, 0.f, 0.f};                                        \
        z      = __builtin_amdgcn_mfma_f32_16x16x32_bf16(k0, qf[0], z, 0, 0, 0);      \
        sa[cb] = __builtin_amdgcn_mfma_f32_16x16x32_bf16(k1, qf[1], z, 0, 0, 0);      \
      }                                                                               \
      _Pragma("unroll")                                                               \
      for (int cb = 0; cb < 4; ++cb) {                                                \
        const f32x4 pv = *(const f32x4*)(pmw + li * 64 + (((cb * 4 + g) ^ (li & 7)) << 2)); \
        f32x4 pmc;                                                                    \
        pmc.x = fmaf(pv.x + MCUR[cb].x, LOG2E, -MSHIFT_);                             \
        pmc.y = fmaf(pv.y + MCUR[cb].y, LOG2E, -MSHIFT_);                             \
        pmc.z = fmaf(pv.z + MCUR[cb].z, LOG2E, -MSHIFT_);                             \
        pmc.w = fmaf(pv.w + MCUR[cb].w, LOG2E, -MSHIFT_);                             \
        const float e0 = exp2f(sa[cb][0] + pmc.x);                                    \
        const float e1 = exp2f(sa[cb][1] + pmc.y);                                    \
        const float e2 = exp2f(sa[cb][2] + pmc.z);                                    \
        const float e3 = exp2f(sa[cb][3] + pmc.w);                                    \
        lrun += (e0 + e1) + (e2 + e3);                                                \
        ushort4 pw;                                                                   \
        pw.x = f2b(e0); pw.y = f2b(e1); pw.z = f2b(e2); pw.w = f2b(e3);               \
        *(ushort4*)&p_lds[wv][li][cb * 16 + g * 4] = pw;                              \
      }                                                                               \
      bf16x8 pf0 = *(const bf16x8*)&p_lds[wv][li][g * 8];                             \
      bf16x8 pf1 = *(const bf16x8*)&p_lds[wv][li][32 + g * 8];                        \
      _Pragma("unroll")                                                               \
      for (int d = 0; d < 4; ++d) {                                                   \
        const int r = d * 16 + li;                                                    \
        const bf16x8 v0 = *(const bf16x8*)(vb + r * 64 + ((g ^ (li & 7)) << 3));      \
        const bf16x8 v1 = *(const bf16x8*)(vb + r * 64 + (((4 + g) ^ (li & 7)) << 3)); \
        ctx[d] = __builtin_amdgcn_mfma_f32_16x16x32_bf16(pf0, v0, ctx[d], 0, 0, 0);   \
        ctx[d] = __builtin_amdgcn_mfma_f32_16x16x32_bf16(pf1, v1, ctx[d], 0, 0, 0);   \
      }                                                                               \
    }                                                                                 \
    __builtin_amdgcn_s_barrier();                                                     \
  }

  for (int t = 0; t < 16; t += 2) {
    PHASE(t,     0, 1, mA, mB);
    PHASE(t + 1, 1, 0, mB, mA);
  }
#undef PHASE
#undef STAGE

  // drain the redundant tail STAGE before LDS deallocation at wave exit
  asm volatile("s_waitcnt vmcnt(0)" ::: "memory");

  // row sums: combine the 4 g-groups (lane li holds partial for q-row li)
  lrun += __shfl_xor(lrun, 16);
  lrun += __shfl_xor(lrun, 32);
#pragma unroll
  for (int j = 0; j < 4; ++j) {
    const float rs = __shfl(lrun, g * 4 + j);
    const float inv = 1.0f / rs;
    const int q = q0 + g * 4 + j;
    float* op = out + ((size_t)b * S_ + q) * D_ + h * HD_ + li;
#pragma unroll
    for (int d = 0; d < 4; ++d)
      op[d * 16] = ctx[d][j] * inv;
  }
}

extern "C" void kernel_launch(void* const* d_in, const int* in_sizes, int n_in,
                              void* d_out, int out_size, void* d_ws, size_t ws_size,
                              hipStream_t stream) {
  const float* hs   = (const float*)d_in[0];
  const float* mask = (const float*)d_in[1];
  const float* prev = (const float*)d_in[2];
  const float* Wq   = (const float*)d_in[3];
  const float* bq   = (const float*)d_in[4];
  const float* Wk   = (const float*)d_in[5];
  const float* bk   = (const float*)d_in[6];
  const float* Wv   = (const float*)d_in[7];
  const float* bv   = (const float*)d_in[8];
  float* out = (float*)d_out;

  char* ws = (char*)d_ws;
  unsigned short* Xbf = (unsigned short*)ws;                    // 16 MB
  unsigned short* Wt  = (unsigned short*)(ws + (16ull << 20));  //  6 MB
  unsigned short* Qw  = (unsigned short*)(ws + (22ull << 20));  // 16 MB
  unsigned short* Kw  = (unsigned short*)(ws + (38ull << 20));  // 16 MB
  unsigned short* Vt  = (unsigned short*)(ws + (54ull << 20));  // 16 MB  (total 70 MB)

  k_convert_x<<<2048, 256, 0, stream>>>(hs, Xbf);
  k_transpose_w<<<dim3(16, 16, 3), 256, 0, stream>>>(Wq, Wk, Wv, Wt);
  k_proj<<<dim3(64, 24), 256, 0, stream>>>(Xbf, Wt, bq, bk, bv, Qw, Kw, Vt);
  k_attn<<<dim3(16, 128), 256, 0, stream>>>(Qw, Kw, Vt, prev, mask, out);
}